// Round 5
// baseline (390.785 us; speedup 1.0000x reference)
//
#include <hip/hip_runtime.h>
#include <hip/hip_bf16.h>

// Problem constants
#define D_M   512
#define H_M   1024
#define G_N   8
#define E_N   8
#define T_N   1024
#define NEXP  64
#define CAP   1024

#define LDK   520          // padded K row stride for xl (bf16 elems): 520*2=1040 B, 16B-aligned

typedef __attribute__((ext_vector_type(8))) short bf16x8;
typedef __attribute__((ext_vector_type(4))) float f32x4;
typedef __attribute__((ext_vector_type(4))) unsigned int u32x4;

// single-instruction packed f32->bf16 (RNE)
__device__ __forceinline__ unsigned pack2(float a, float b) {
  unsigned r;
  asm("v_cvt_pk_bf16_f32 %0, %1, %2" : "=v"(r) : "v"(a), "v"(b));
  return r;
}
__device__ __forceinline__ unsigned short f2bf(float f) {
  unsigned u = __builtin_bit_cast(unsigned, f);
  u = (u + 0x7fffu + ((u >> 16) & 1u)) >> 16;   // RTN-even
  return (unsigned short)u;
}

// ---------------- routing (fp32, exact) + expert-list build (merged) ----------------
__global__ __launch_bounds__(64) void k_route(
    const float* __restrict__ x, const float* __restrict__ g1,
    const float* __restrict__ g2, float* __restrict__ slotW,
    int* __restrict__ counts, int* __restrict__ list) {
  __shared__ float xs[D_M];
  __shared__ float l2s[G_N][E_N];
  __shared__ float l1s[G_N];
  __shared__ float l1part[G_N][8];
  const int t = blockIdx.x;
  const int lane = threadIdx.x;
  const float* xr = x + (size_t)t * D_M;
  for (int i = lane; i < D_M; i += 64) xs[i] = xr[i];
  __syncthreads();
  {
    const int g = lane >> 3, e = lane & 7;
    const float* gp = g2 + (size_t)g * D_M * E_N + e;
    float acc = 0.f;
    #pragma unroll 8
    for (int i = 0; i < D_M; i++) acc += xs[i] * gp[(size_t)i * E_N];
    l2s[g][e] = acc;
  }
  {
    const int g = lane >> 3, c = lane & 7;
    float acc = 0.f;
    #pragma unroll 8
    for (int i = c * 64; i < c * 64 + 64; i++) acc += xs[i] * g1[(size_t)i * G_N + g];
    l1part[g][c] = acc;
  }
  __syncthreads();
  if (lane < G_N) {
    float s = 0.f;
    #pragma unroll
    for (int c = 0; c < 8; c++) s += l1part[lane][c];
    l1s[lane] = s;
  }
  __syncthreads();
  if (lane == 0) {
    int a1 = 0;
    for (int g = 1; g < G_N; g++) if (l1s[g] > l1s[a1]) a1 = g;
    int a2 = (a1 == 0) ? 1 : 0;
    for (int g = 0; g < G_N; g++) if (g != a1 && l1s[g] > l1s[a2]) a2 = g;
    const float m = l1s[a1];
    float w1a = __expf(l1s[a1] - m), w1b = __expf(l1s[a2] - m);
    const float inv = 1.f / (w1a + w1b);
    w1a *= inv; w1b *= inv;
    const int gsel[2] = {a1, a2};
    const float wsel[2] = {w1a, w1b};
    for (int a = 0; a < 2; a++) {
      const int g = gsel[a];
      int e1 = 0;
      for (int e = 1; e < E_N; e++) if (l2s[g][e] > l2s[g][e1]) e1 = e;
      int e2 = (e1 == 0) ? 1 : 0;
      for (int e = 0; e < E_N; e++) if (e != e1 && l2s[g][e] > l2s[g][e2]) e2 = e;
      const float mm = l2s[g][e1];
      float ua = __expf(l2s[g][e1] - mm), ub = __expf(l2s[g][e2] - mm);
      const float uin = 1.f / (ua + ub);
      ua *= uin; ub *= uin;
      const int ge0 = g * E_N + e1;
      const int ge1 = g * E_N + e2;
      slotW[t * 4 + a * 2 + 0] = wsel[a] * ua;
      slotW[t * 4 + a * 2 + 1] = wsel[a] * ub;
      int p0 = atomicAdd(&counts[ge0], 1);
      list[ge0 * CAP + p0] = t * 4 + a * 2 + 0;
      int p1 = atomicAdd(&counts[ge1], 1);
      list[ge1 * CAP + p1] = t * 4 + a * 2 + 1;
    }
  }
}

// ---------------- GEMM1: h = relu(x @ W1 + b1) -> bf16 ----------------
// grid: 64 ge x 16 j-tiles(64). block 256 = 4 waves; wave owns 16 j, all 64 tokens (mt=4).
// W-tile (512k x 64j) staged COALESCED (f32x4 along j) -> LDS in MFMA-fragment order (bf16),
// then K-loop reads frags as contiguous conflict-free ds_read_b128. No strided global W access.
__global__ __launch_bounds__(256, 1) void k_mlp1(
    const float* __restrict__ x, const float* __restrict__ W1,
    const float* __restrict__ b1, const int* __restrict__ counts,
    const int* __restrict__ list, unsigned short* __restrict__ h_ws) {
  const int ge = blockIdx.x >> 4;
  const int jt = blockIdx.x & 15;
  const int jbase = jt * 64;
  const int n = counts[ge];
  if (n == 0) return;
  __shared__ unsigned short wl[4 * 16 * 64 * 8];  // [w][s][lane][8] bf16 = 64 KB
  __shared__ unsigned short xl[64 * LDK];         // [token][k] full-K, bf16 (66.5 KB)
  __shared__ int tokTS[64];
  const int tid = threadIdx.x;
  const int lane = tid & 63, wave = tid >> 6;
  const int m16 = lane & 15, quad = lane >> 4;

  const float bv = b1[ge * H_M + jbase + wave * 16 + m16];

  // ---- W stage: coalesced read (f32x4 along j), fragment-order LDS write ----
  {
    const float* Wg = W1 + (size_t)ge * (D_M * H_M) + jbase;
    const int rgrp = tid >> 4;        // 16 rows per pass
    const int lidx = tid & 15;        // 16 lanes x f32x4 = 64 cols
    const int wp = lidx >> 2;
    const int m16b = (lidx & 3) * 4;
    #pragma unroll 4
    for (int pass = 0; pass < 32; pass++) {
      const int r = pass * 16 + rgrp;               // k row 0..511
      f32x4 v = *(const f32x4*)(Wg + (size_t)r * H_M + lidx * 4);
      const int s = r >> 5, q = (r >> 3) & 3, i = r & 7;
      unsigned p0 = pack2(v.x, v.y), p1 = pack2(v.z, v.w);
      unsigned short* base = &wl[((wp * 16 + s) * 64 + q * 16 + m16b) * 8 + i];
      base[0 * 8] = (unsigned short)p0;
      base[1 * 8] = (unsigned short)(p0 >> 16);
      base[2 * 8] = (unsigned short)p1;
      base[3 * 8] = (unsigned short)(p1 >> 16);
    }
  }

  for (int t0 = 0; t0 < n; t0 += 64) {
    __syncthreads();
    if (tid < 64) {
      int idx = t0 + tid;
      tokTS[tid] = list[ge * CAP + (idx < n ? idx : n - 1)];
    }
    __syncthreads();
    // stage x (fp32 -> bf16): thread covers token tid>>2, k-lane (tid&3)*4, 32 reps of 16 floats
    {
      const int trow = tid >> 2;
      const int kb = (tid & 3) * 4;
      const float* xr = x + (size_t)(tokTS[trow] >> 2) * D_M + kb;
      unsigned short* dst = &xl[trow * LDK + kb];
      #pragma unroll 8
      for (int rep = 0; rep < 32; rep++) {
        f32x4 v = *(const f32x4*)(xr + rep * 16);
        uint2 p = { pack2(v.x, v.y), pack2(v.z, v.w) };
        *(uint2*)(dst + rep * 16) = p;
      }
    }
    __syncthreads();

    f32x4 acc[4] = {};
    #pragma unroll
    for (int s = 0; s < 16; s++) {
      bf16x8 wfrag = *(const bf16x8*)&wl[((wave * 16 + s) * 64 + lane) * 8];
      #pragma unroll
      for (int mt = 0; mt < 4; mt++) {
        bf16x8 af = *(bf16x8*)&xl[(mt * 16 + m16) * LDK + s * 32 + quad * 8];
        acc[mt] = __builtin_amdgcn_mfma_f32_16x16x32_bf16(af, wfrag, acc[mt], 0, 0, 0);
      }
    }
    // epilogue: bias + relu -> bf16
    #pragma unroll
    for (int mt = 0; mt < 4; mt++)
      #pragma unroll
      for (int i = 0; i < 4; i++) {
        const int tr = mt * 16 + quad * 4 + i;
        if (t0 + tr < n) {
          const int ts = tokTS[tr];
          float v = acc[mt][i] + bv;
          h_ws[(size_t)ts * H_M + jbase + wave * 16 + m16] = f2bf(v > 0.f ? v : 0.f);
        }
      }
  }
}

// ---------------- GEMM2: y_part = h @ W2 (+b2 on ks=0) -> fp32, K-split 2 ----------------
// grid: 64 ge x 8 j-tiles(64) x 2 ksplit. Same coalesced W staging.
__global__ __launch_bounds__(256, 1) void k_mlp2(
    const unsigned short* __restrict__ h_ws, const float* __restrict__ W2,
    const float* __restrict__ b2, const int* __restrict__ counts,
    const int* __restrict__ list, float* __restrict__ y0,
    float* __restrict__ y1) {
  const int ge = blockIdx.x >> 4;
  const int jt = (blockIdx.x >> 1) & 7;
  const int jbase = jt * 64;
  const int ks = blockIdx.x & 1;
  const int n = counts[ge];
  if (n == 0) return;
  __shared__ unsigned short wl[4 * 16 * 64 * 8];  // 64 KB
  __shared__ unsigned short xl[64 * LDK];         // [token][k-half], bf16
  __shared__ int tokTS[64];
  const int tid = threadIdx.x;
  const int lane = tid & 63, wave = tid >> 6;
  const int m16 = lane & 15, quad = lane >> 4;

  const float bv = ks == 0 ? b2[ge * D_M + jbase + wave * 16 + m16] : 0.f;
  float* yk = ks == 0 ? y0 : y1;

  // ---- W stage: coalesced read, fragment-order LDS write ----
  {
    const float* Wg = W2 + (size_t)ge * (H_M * D_M) + (size_t)(ks * 512) * D_M + jbase;
    const int rgrp = tid >> 4;
    const int lidx = tid & 15;
    const int wp = lidx >> 2;
    const int m16b = (lidx & 3) * 4;
    #pragma unroll 4
    for (int pass = 0; pass < 32; pass++) {
      const int r = pass * 16 + rgrp;               // local k row 0..511
      f32x4 v = *(const f32x4*)(Wg + (size_t)r * D_M + lidx * 4);
      const int s = r >> 5, q = (r >> 3) & 3, i = r & 7;
      unsigned p0 = pack2(v.x, v.y), p1 = pack2(v.z, v.w);
      unsigned short* base = &wl[((wp * 16 + s) * 64 + q * 16 + m16b) * 8 + i];
      base[0 * 8] = (unsigned short)p0;
      base[1 * 8] = (unsigned short)(p0 >> 16);
      base[2 * 8] = (unsigned short)p1;
      base[3 * 8] = (unsigned short)(p1 >> 16);
    }
  }

  for (int t0 = 0; t0 < n; t0 += 64) {
    __syncthreads();
    if (tid < 64) {
      int idx = t0 + tid;
      tokTS[tid] = list[ge * CAP + (idx < n ? idx : n - 1)];
    }
    __syncthreads();
    // stage h-half (already bf16): thread covers token tid>>2, k-lane (tid&3)*8, 16 reps of 32 elems
    {
      const int trow = tid >> 2;
      const int kb = (tid & 3) * 8;
      const unsigned short* hr = h_ws + (size_t)tokTS[trow] * H_M + ks * 512 + kb;
      unsigned short* dst = &xl[trow * LDK + kb];
      #pragma unroll 8
      for (int rep = 0; rep < 16; rep++)
        *(u32x4*)(dst + rep * 32) = *(const u32x4*)(hr + rep * 32);
    }
    __syncthreads();

    f32x4 acc[4] = {};
    #pragma unroll
    for (int s = 0; s < 16; s++) {
      bf16x8 wfrag = *(const bf16x8*)&wl[((wave * 16 + s) * 64 + lane) * 8];
      #pragma unroll
      for (int mt = 0; mt < 4; mt++) {
        bf16x8 af = *(bf16x8*)&xl[(mt * 16 + m16) * LDK + s * 32 + quad * 8];
        acc[mt] = __builtin_amdgcn_mfma_f32_16x16x32_bf16(af, wfrag, acc[mt], 0, 0, 0);
      }
    }
    #pragma unroll
    for (int mt = 0; mt < 4; mt++)
      #pragma unroll
      for (int i = 0; i < 4; i++) {
        const int tr = mt * 16 + quad * 4 + i;
        if (t0 + tr < n) {
          const int ts = tokTS[tr];
          yk[(size_t)ts * D_M + jbase + wave * 16 + m16] = acc[mt][i] + bv;
        }
      }
  }
}

// ---------------- combine: out[t] = sum_s slotW[t,s] * (y0+y1)[t*4+s] ----------------
__global__ __launch_bounds__(256) void k_combine(
    const float* __restrict__ y0, const float* __restrict__ y1,
    const float* __restrict__ slotW, float* __restrict__ out) {
  const int idx = blockIdx.x * 256 + threadIdx.x;
  if (idx >= T_N * D_M / 4) return;
  const int t = idx >> 7;
  const int j = (idx & 127) * 4;
  float4 r = {0.f, 0.f, 0.f, 0.f};
  #pragma unroll
  for (int s = 0; s < 4; s++) {
    const float w = slotW[t * 4 + s];
    const size_t off = (size_t)(t * 4 + s) * D_M + j;
    const float4 a = *(const float4*)(y0 + off);
    const float4 b = *(const float4*)(y1 + off);
    r.x += w * (a.x + b.x);
    r.y += w * (a.y + b.y);
    r.z += w * (a.z + b.z);
    r.w += w * (a.w + b.w);
  }
  *(float4*)&out[(size_t)t * D_M + j] = r;
}

// ---------------- launch ----------------
extern "C" void kernel_launch(void* const* d_in, const int* in_sizes, int n_in,
                              void* d_out, int out_size, void* d_ws, size_t ws_size,
                              hipStream_t stream) {
  const float* x  = (const float*)d_in[0];
  const float* g1 = (const float*)d_in[1];
  const float* g2 = (const float*)d_in[2];
  const float* W1 = (const float*)d_in[3];
  const float* b1 = (const float*)d_in[4];
  const float* W2 = (const float*)d_in[5];
  const float* b2 = (const float*)d_in[6];
  float* out = (float*)d_out;

  char* ws = (char*)d_ws;
  float*          slotW  = (float*)(ws + 16384);               // 4096 floats
  int*            counts = (int*)(ws + 32768);                 // 64 ints
  int*            list   = (int*)(ws + 36864);                 // 64*1024 ints (256 KB)
  unsigned short* h_ws   = (unsigned short*)(ws + 524288);     // 4096*1024 bf16 (8 MB)
  float*          y0     = (float*)(ws + 524288 + 8388608);    // 4096*512 f32 (8 MB)
  float*          y1     = (float*)(ws + 524288 + 16777216);   // 4096*512 f32 (8 MB)

  hipMemsetAsync(counts, 0, NEXP * sizeof(int), stream);
  k_route<<<T_N, 64, 0, stream>>>(x, g1, g2, slotW, counts, list);
  k_mlp1<<<NEXP * 16, 256, 0, stream>>>(x, W1, b1, counts, list, h_ws);
  k_mlp2<<<NEXP * 16, 256, 0, stream>>>(h_ws, W2, b2, counts, list, y0, y1);
  k_combine<<<(T_N * D_M / 4) / 256, 256, 0, stream>>>(y0, y1, slotW, out);
}